// Round 1
// baseline (360.835 us; speedup 1.0000x reference)
//
#include <hip/hip_runtime.h>

// Problem dims (fixed by setup_inputs): B=1, C=32, H=W=1024, fp32.
constexpr int C  = 32;
constexpr int H  = 1024;
constexpr int W  = 1024;
constexpr int HW = H * W;

// ---------------------------------------------------------------------------
// Pass 1: transpose x [C,H,W] -> xp [H*W][C] (pixel-major, 128 B per pixel).
// (unchanged from previous round)
// ---------------------------------------------------------------------------
constexpr int TP_PX   = 256;
constexpr int LDS_PAD = 260;   // 256 + 4: keeps 16B alignment, breaks bank aliasing

__global__ __launch_bounds__(256) void transpose_kernel(
    const float* __restrict__ x, float* __restrict__ xp)
{
    __shared__ float lds[C * LDS_PAD];   // 33.3 KB
    const int p0 = blockIdx.x * TP_PX;
    const int t  = threadIdx.x;
    const int pl = t & 63;     // float4 index within 256-px tile (per wave)
    const int cg = t >> 6;     // wave id -> channel subgroup

    const float4* __restrict__ x4 = (const float4*)x;

    float4 v[8];
#pragma unroll
    for (int i = 0; i < 8; ++i) {
        const int c = i * 4 + cg;
        v[i] = x4[(size_t)c * (HW / 4) + (p0 >> 2) + pl];
    }
    __builtin_amdgcn_sched_barrier(0);

#pragma unroll
    for (int i = 0; i < 8; ++i) {
        const int c = i * 4 + cg;
        *(float4*)&lds[c * LDS_PAD + pl * 4] = v[i];
    }
    __syncthreads();

    float4* __restrict__ xp4 = (float4*)xp + (size_t)p0 * 8;
#pragma unroll
    for (int m = 0; m < 8; ++m) {
        const int f  = m * 256 + t;
        const int px = f >> 3;
        const int j  = f & 7;
        float4 o;
        o.x = lds[(j * 4 + 0) * LDS_PAD + px];
        o.y = lds[(j * 4 + 1) * LDS_PAD + px];
        o.z = lds[(j * 4 + 2) * LDS_PAD + px];
        o.w = lds[(j * 4 + 3) * LDS_PAD + px];
        xp4[f] = o;
    }
}

// ---------------------------------------------------------------------------
// Pass 2 (NEW): 8 lanes per pixel. Lane j = t&7 owns channels 4j..4j+3, so
// one wave load instruction for a corner covers 8 pixels x one FULL 128 B
// line each (8 line-touches/instr vs 64 in the thread-per-pixel version).
// 2 pixels per lane => 8 x 16 B loads batched in flight.
// XCD-chunked blockIdx swizzle: each XCD gets a contiguous 128-row band so
// the bilinear corner reuse stays inside one L2 instead of being replicated
// across all 8 XCD L2s.
// ---------------------------------------------------------------------------
constexpr int GPX_BLOCK = 64;             // pixels per 256-thread block

__global__ __launch_bounds__(256) void gather8_kernel(
    const float* __restrict__ flow,
    const float* __restrict__ xp,
    float* __restrict__ out)
{
    // Bijective chunked swizzle (nwg = 16384, divisible by 8):
    // hardware round-robins blockIdx across XCDs; remap so XCD k processes
    // logical blocks [k*nwg/8, (k+1)*nwg/8) in order.
    const int nwg = gridDim.x;
    const int nb  = (blockIdx.x & 7) * (nwg >> 3) + (blockIdx.x >> 3);

    const int t  = threadIdx.x;
    const int j  = t & 7;      // float4 (channel quad) within pixel record
    const int pl = t >> 3;     // pixel slot within block half (0..31)

    const int pxbase = nb * GPX_BLOCK;

    const float4* __restrict__ xq = (const float4*)xp;

    int   pix[2];
    int   b00[2], b10[2], b01[2], b11[2];
    float w00[2], w10[2], w01[2], w11[2];

#pragma unroll
    for (int q = 0; q < 2; ++q) {
        const int p = pxbase + q * 32 + pl;
        pix[q] = p;
        const int w_ = p & (W - 1);
        const int h_ = p >> 10;

        const float fx = flow[p];
        const float fy = flow[HW + p];

        // Mirror reference arithmetic order exactly (fp32).
        const float gx = (fx + (float)w_) / (float)(W - 1) * 2.0f - 1.0f;
        const float gy = (fy + (float)h_) / (float)(H - 1) * 2.0f - 1.0f;
        const float ix = ((gx + 1.0f) * (float)W - 1.0f) * 0.5f;
        const float iy = ((gy + 1.0f) * (float)H - 1.0f) * 0.5f;

        const float x0f = floorf(ix);
        const float y0f = floorf(iy);
        const float wx1 = ix - x0f;
        const float wy1 = iy - y0f;
        const float wx0 = 1.0f - wx1;
        const float wy0 = 1.0f - wy1;

        const int x0 = (int)x0f;
        const int y0 = (int)y0f;
        const int x1 = x0 + 1;
        const int y1 = y0 + 1;

        const float vx0 = (x0 >= 0 && x0 < W) ? 1.0f : 0.0f;
        const float vx1 = (x1 >= 0 && x1 < W) ? 1.0f : 0.0f;
        const float vy0 = (y0 >= 0 && y0 < H) ? 1.0f : 0.0f;
        const float vy1 = (y1 >= 0 && y1 < H) ? 1.0f : 0.0f;

        w00[q] = wx0 * wy0 * vx0 * vy0;
        w10[q] = wx1 * wy0 * vx1 * vy0;
        w01[q] = wx0 * wy1 * vx0 * vy1;
        w11[q] = wx1 * wy1 * vx1 * vy1;

        const int xc0 = min(max(x0, 0), W - 1);
        const int xc1 = min(max(x1, 0), W - 1);
        const int yc0 = min(max(y0, 0), H - 1);
        const int yc1 = min(max(y1, 0), H - 1);

        b00[q] = (yc0 * W + xc0) * 8 + j;
        b10[q] = (yc0 * W + xc1) * 8 + j;
        b01[q] = (yc1 * W + xc0) * 8 + j;
        b11[q] = (yc1 * W + xc1) * 8 + j;
    }

    // Batch all 8 corner loads (8 x 16 B outstanding per lane).
    float4 va[2], vb[2], vc[2], vd[2];
#pragma unroll
    for (int q = 0; q < 2; ++q) {
        va[q] = xq[b00[q]];
        vb[q] = xq[b10[q]];
        vc[q] = xq[b01[q]];
        vd[q] = xq[b11[q]];
    }
    __builtin_amdgcn_sched_barrier(0);   // keep loads hoisted/batched

    float4 acc[2];
#pragma unroll
    for (int q = 0; q < 2; ++q) {
        acc[q].x = va[q].x * w00[q] + vb[q].x * w10[q];
        acc[q].y = va[q].y * w00[q] + vb[q].y * w10[q];
        acc[q].z = va[q].z * w00[q] + vb[q].z * w10[q];
        acc[q].w = va[q].w * w00[q] + vb[q].w * w10[q];
        acc[q].x += vc[q].x * w01[q] + vd[q].x * w11[q];
        acc[q].y += vc[q].y * w01[q] + vd[q].y * w11[q];
        acc[q].z += vc[q].z * w01[q] + vd[q].z * w11[q];
        acc[q].w += vc[q].w * w01[q] + vd[q].w * w11[q];
    }

    // Stores: lane writes its 4 channels of its pixel. Per wave instruction:
    // 8 x 32 B contiguous segments; the block's 4 waves fill each 128 B out
    // line, so L2 merges to full lines before HBM.
#pragma unroll
    for (int q = 0; q < 2; ++q) {
        out[(size_t)(j * 4 + 0) * HW + pix[q]] = acc[q].x;
        out[(size_t)(j * 4 + 1) * HW + pix[q]] = acc[q].y;
        out[(size_t)(j * 4 + 2) * HW + pix[q]] = acc[q].z;
        out[(size_t)(j * 4 + 3) * HW + pix[q]] = acc[q].w;
    }
}

// ---------------------------------------------------------------------------
// Fallback (round-1 kernel) if workspace is too small for the transposed copy.
// ---------------------------------------------------------------------------
__global__ __launch_bounds__(256) void stn_warp_fallback(
    const float* __restrict__ flow,
    const float* __restrict__ x,
    float* __restrict__ out)
{
    const int tid = blockIdx.x * blockDim.x + threadIdx.x;
    if (tid >= HW) return;

    const int w = tid & (W - 1);
    const int h = tid >> 10;

    const float fx = flow[tid];
    const float fy = flow[HW + tid];

    const float gx = (fx + (float)w) / (float)(W - 1) * 2.0f - 1.0f;
    const float gy = (fy + (float)h) / (float)(H - 1) * 2.0f - 1.0f;
    const float ix = ((gx + 1.0f) * (float)W - 1.0f) * 0.5f;
    const float iy = ((gy + 1.0f) * (float)H - 1.0f) * 0.5f;

    const float x0f = floorf(ix);
    const float y0f = floorf(iy);
    const float wx1 = ix - x0f;
    const float wy1 = iy - y0f;
    const float wx0 = 1.0f - wx1;
    const float wy0 = 1.0f - wy1;

    const int x0 = (int)x0f;
    const int y0 = (int)y0f;
    const int x1 = x0 + 1;
    const int y1 = y0 + 1;

    const float vx0 = (x0 >= 0 && x0 < W) ? 1.0f : 0.0f;
    const float vx1 = (x1 >= 0 && x1 < W) ? 1.0f : 0.0f;
    const float vy0 = (y0 >= 0 && y0 < H) ? 1.0f : 0.0f;
    const float vy1 = (y1 >= 0 && y1 < H) ? 1.0f : 0.0f;

    const float w00 = wx0 * wy0 * vx0 * vy0;
    const float w10 = wx1 * wy0 * vx1 * vy0;
    const float w01 = wx0 * wy1 * vx0 * vy1;
    const float w11 = wx1 * wy1 * vx1 * vy1;

    const int xc0 = min(max(x0, 0), W - 1);
    const int xc1 = min(max(x1, 0), W - 1);
    const int yc0 = min(max(y0, 0), H - 1);
    const int yc1 = min(max(y1, 0), H - 1);

    const int o00 = yc0 * W + xc0;
    const int o10 = yc0 * W + xc1;
    const int o01 = yc1 * W + xc0;
    const int o11 = yc1 * W + xc1;

#pragma unroll
    for (int c = 0; c < C; ++c) {
        const float* __restrict__ xc = x + c * HW;
        const float v = xc[o00] * w00 + xc[o10] * w10
                      + xc[o01] * w01 + xc[o11] * w11;
        out[c * HW + tid] = v;
    }
}

extern "C" void kernel_launch(void* const* d_in, const int* in_sizes, int n_in,
                              void* d_out, int out_size, void* d_ws, size_t ws_size,
                              hipStream_t stream) {
    const float* flow = (const float*)d_in[0];  // [1,2,1024,1024]
    const float* x    = (const float*)d_in[1];  // [1,32,1024,1024]
    float* out        = (float*)d_out;          // [1,32,1024,1024]

    const size_t need = (size_t)HW * C * sizeof(float);  // 128 MB
    if (ws_size >= need) {
        float* xp = (float*)d_ws;
        transpose_kernel<<<HW / TP_PX, 256, 0, stream>>>(x, xp);
        gather8_kernel<<<HW / GPX_BLOCK, 256, 0, stream>>>(flow, xp, out);
    } else {
        stn_warp_fallback<<<HW / 256, 256, 0, stream>>>(flow, x, out);
    }
}

// Round 2
// 322.717 us; speedup vs baseline: 1.1181x; 1.1181x over previous
//
#include <hip/hip_runtime.h>

// Problem dims (fixed by setup_inputs): B=1, C=32, H=W=1024, fp32.
constexpr int C  = 32;
constexpr int H  = 1024;
constexpr int W  = 1024;
constexpr int HW = H * W;

// ---------------------------------------------------------------------------
// Pass 1: transpose x [C,H,W] -> xp [H*W][C] (pixel-major, 128 B per pixel).
// (unchanged)
// ---------------------------------------------------------------------------
constexpr int TP_PX   = 256;
constexpr int LDS_PAD = 260;   // 256 + 4: keeps 16B alignment, breaks bank aliasing

__global__ __launch_bounds__(256) void transpose_kernel(
    const float* __restrict__ x, float* __restrict__ xp)
{
    __shared__ float lds[C * LDS_PAD];   // 33.3 KB
    const int p0 = blockIdx.x * TP_PX;
    const int t  = threadIdx.x;
    const int pl = t & 63;     // float4 index within 256-px tile (per wave)
    const int cg = t >> 6;     // wave id -> channel subgroup

    const float4* __restrict__ x4 = (const float4*)x;

    float4 v[8];
#pragma unroll
    for (int i = 0; i < 8; ++i) {
        const int c = i * 4 + cg;
        v[i] = x4[(size_t)c * (HW / 4) + (p0 >> 2) + pl];
    }
    __builtin_amdgcn_sched_barrier(0);

#pragma unroll
    for (int i = 0; i < 8; ++i) {
        const int c = i * 4 + cg;
        *(float4*)&lds[c * LDS_PAD + pl * 4] = v[i];
    }
    __syncthreads();

    float4* __restrict__ xp4 = (float4*)xp + (size_t)p0 * 8;
#pragma unroll
    for (int m = 0; m < 8; ++m) {
        const int f  = m * 256 + t;
        const int px = f >> 3;
        const int j  = f & 7;
        float4 o;
        o.x = lds[(j * 4 + 0) * LDS_PAD + px];
        o.y = lds[(j * 4 + 1) * LDS_PAD + px];
        o.z = lds[(j * 4 + 2) * LDS_PAD + px];
        o.w = lds[(j * 4 + 3) * LDS_PAD + px];
        xp4[f] = o;
    }
}

// ---------------------------------------------------------------------------
// Pass 2 v3: minimize vmem wave-instructions per pixel (measured limiter:
// ~59 cyc per vmem instruction per CU regardless of coalescing).
//   gather: 0.5 instr/px (floor: 512 B corner data, 16 B/lane)  [8-lane/px]
//   stores: 0.125 instr/px (LDS-staged channel transpose, 512 B segments)
//   flow:   0.03 instr/px (phase-A coalesced, params staged in LDS)
// Total ~0.66 instr/px vs 1.25 in v2.
// ---------------------------------------------------------------------------
constexpr int GP_PX   = 128;            // pixels per 256-thread block
constexpr int RES_PAD = GP_PX + 5;      // 133: spreads bank stride on res[][]

__global__ __launch_bounds__(256) void gather_v3(
    const float* __restrict__ flow,
    const float* __restrict__ xp,
    float* __restrict__ out)
{
    __shared__ float prm[GP_PX][8];       // w00,w10,w01,w11, b00,b10,b01,b11  (4 KB)
    __shared__ float res[C][RES_PAD];     // staged output, px-major per channel (17 KB)

    // Bijective chunked XCD swizzle (nwg = 8192, divisible by 8).
    const int nwg = gridDim.x;
    const int nb  = (blockIdx.x & 7) * (nwg >> 3) + (blockIdx.x >> 3);
    const int pxbase = nb * GP_PX;
    const int t = threadIdx.x;

    // ---- Phase A: per-pixel coords/weights, coalesced flow loads ----------
    if (t < GP_PX) {
        const int p  = pxbase + t;
        const int w_ = p & (W - 1);
        const int h_ = p >> 10;

        const float fx = flow[p];
        const float fy = flow[HW + p];

        // Mirror reference arithmetic order exactly (fp32).
        const float gx = (fx + (float)w_) / (float)(W - 1) * 2.0f - 1.0f;
        const float gy = (fy + (float)h_) / (float)(H - 1) * 2.0f - 1.0f;
        const float ix = ((gx + 1.0f) * (float)W - 1.0f) * 0.5f;
        const float iy = ((gy + 1.0f) * (float)H - 1.0f) * 0.5f;

        const float x0f = floorf(ix);
        const float y0f = floorf(iy);
        const float wx1 = ix - x0f;
        const float wy1 = iy - y0f;
        const float wx0 = 1.0f - wx1;
        const float wy0 = 1.0f - wy1;

        const int x0 = (int)x0f;
        const int y0 = (int)y0f;
        const int x1 = x0 + 1;
        const int y1 = y0 + 1;

        const float vx0 = (x0 >= 0 && x0 < W) ? 1.0f : 0.0f;
        const float vx1 = (x1 >= 0 && x1 < W) ? 1.0f : 0.0f;
        const float vy0 = (y0 >= 0 && y0 < H) ? 1.0f : 0.0f;
        const float vy1 = (y1 >= 0 && y1 < H) ? 1.0f : 0.0f;

        const int xc0 = min(max(x0, 0), W - 1);
        const int xc1 = min(max(x1, 0), W - 1);
        const int yc0 = min(max(y0, 0), H - 1);
        const int yc1 = min(max(y1, 0), H - 1);

        prm[t][0] = wx0 * wy0 * vx0 * vy0;
        prm[t][1] = wx1 * wy0 * vx1 * vy0;
        prm[t][2] = wx0 * wy1 * vx0 * vy1;
        prm[t][3] = wx1 * wy1 * vx1 * vy1;
        prm[t][4] = __int_as_float((yc0 * W + xc0) * 8);
        prm[t][5] = __int_as_float((yc0 * W + xc1) * 8);
        prm[t][6] = __int_as_float((yc1 * W + xc0) * 8);
        prm[t][7] = __int_as_float((yc1 * W + xc1) * 8);
    }
    __syncthreads();

    // ---- Phase B: gather. 8 lanes per pixel (lane j owns channels 4j..4j+3),
    // each gather instr = 8 px x one full 128 B record. 4 px per thread. ----
    const int j  = t & 7;
    const int pl = t >> 3;              // 0..31
    const float4* __restrict__ xq = (const float4*)xp;

    float4 w4[4];
    int4   b4[4];
#pragma unroll
    for (int k = 0; k < 4; ++k) {
        const int px = k * 32 + pl;
        w4[k] = *(const float4*)&prm[px][0];
        const float4 bb = *(const float4*)&prm[px][4];
        b4[k].x = __float_as_int(bb.x) + j;
        b4[k].y = __float_as_int(bb.y) + j;
        b4[k].z = __float_as_int(bb.z) + j;
        b4[k].w = __float_as_int(bb.w) + j;
    }

    float4 acc[4];
#pragma unroll
    for (int kk = 0; kk < 2; ++kk) {
        const int k0 = 2 * kk + 0;
        const int k1 = 2 * kk + 1;
        // 8 corner loads batched (8 x 16 B outstanding per lane).
        float4 va0 = xq[b4[k0].x];
        float4 vb0 = xq[b4[k0].y];
        float4 vc0 = xq[b4[k0].z];
        float4 vd0 = xq[b4[k0].w];
        float4 va1 = xq[b4[k1].x];
        float4 vb1 = xq[b4[k1].y];
        float4 vc1 = xq[b4[k1].z];
        float4 vd1 = xq[b4[k1].w];
        __builtin_amdgcn_sched_barrier(0);

        acc[k0].x = va0.x * w4[k0].x + vb0.x * w4[k0].y;
        acc[k0].y = va0.y * w4[k0].x + vb0.y * w4[k0].y;
        acc[k0].z = va0.z * w4[k0].x + vb0.z * w4[k0].y;
        acc[k0].w = va0.w * w4[k0].x + vb0.w * w4[k0].y;
        acc[k0].x += vc0.x * w4[k0].z + vd0.x * w4[k0].w;
        acc[k0].y += vc0.y * w4[k0].z + vd0.y * w4[k0].w;
        acc[k0].z += vc0.z * w4[k0].z + vd0.z * w4[k0].w;
        acc[k0].w += vc0.w * w4[k0].z + vd0.w * w4[k0].w;

        acc[k1].x = va1.x * w4[k1].x + vb1.x * w4[k1].y;
        acc[k1].y = va1.y * w4[k1].x + vb1.y * w4[k1].y;
        acc[k1].z = va1.z * w4[k1].x + vb1.z * w4[k1].y;
        acc[k1].w = va1.w * w4[k1].x + vb1.w * w4[k1].y;
        acc[k1].x += vc1.x * w4[k1].z + vd1.x * w4[k1].w;
        acc[k1].y += vc1.y * w4[k1].z + vd1.y * w4[k1].w;
        acc[k1].z += vc1.z * w4[k1].z + vd1.z * w4[k1].w;
        acc[k1].w += vc1.w * w4[k1].z + vd1.w * w4[k1].w;
    }

    // ---- Phase C: stage results to LDS (px-major per channel) -------------
#pragma unroll
    for (int k = 0; k < 4; ++k) {
        const int px = k * 32 + pl;
        res[4 * j + 0][px] = acc[k].x;
        res[4 * j + 1][px] = acc[k].y;
        res[4 * j + 2][px] = acc[k].z;
        res[4 * j + 3][px] = acc[k].w;
    }
    __syncthreads();

    // ---- Phase D: coalesced float4 stores over channel planes -------------
    // 1024 float4 per block = 4 per thread; each wave-instr = 2 x 512 B
    // contiguous segments.
    float4* __restrict__ out4 = (float4*)out;
    const int gbase = pxbase >> 2;
#pragma unroll
    for (int m = 0; m < 4; ++m) {
        const int f = m * 256 + t;
        const int c = f >> 5;          // channel
        const int g = f & 31;          // float4 group within 128-px tile
        float4 o;
        o.x = res[c][4 * g + 0];
        o.y = res[c][4 * g + 1];
        o.z = res[c][4 * g + 2];
        o.w = res[c][4 * g + 3];
        out4[(size_t)c * (HW / 4) + gbase + g] = o;
    }
}

// ---------------------------------------------------------------------------
// Fallback (round-1 kernel) if workspace is too small for the transposed copy.
// ---------------------------------------------------------------------------
__global__ __launch_bounds__(256) void stn_warp_fallback(
    const float* __restrict__ flow,
    const float* __restrict__ x,
    float* __restrict__ out)
{
    const int tid = blockIdx.x * blockDim.x + threadIdx.x;
    if (tid >= HW) return;

    const int w = tid & (W - 1);
    const int h = tid >> 10;

    const float fx = flow[tid];
    const float fy = flow[HW + tid];

    const float gx = (fx + (float)w) / (float)(W - 1) * 2.0f - 1.0f;
    const float gy = (fy + (float)h) / (float)(H - 1) * 2.0f - 1.0f;
    const float ix = ((gx + 1.0f) * (float)W - 1.0f) * 0.5f;
    const float iy = ((gy + 1.0f) * (float)H - 1.0f) * 0.5f;

    const float x0f = floorf(ix);
    const float y0f = floorf(iy);
    const float wx1 = ix - x0f;
    const float wy1 = iy - y0f;
    const float wx0 = 1.0f - wx1;
    const float wy0 = 1.0f - wy1;

    const int x0 = (int)x0f;
    const int y0 = (int)y0f;
    const int x1 = x0 + 1;
    const int y1 = y0 + 1;

    const float vx0 = (x0 >= 0 && x0 < W) ? 1.0f : 0.0f;
    const float vx1 = (x1 >= 0 && x1 < W) ? 1.0f : 0.0f;
    const float vy0 = (y0 >= 0 && y0 < H) ? 1.0f : 0.0f;
    const float vy1 = (y1 >= 0 && y1 < H) ? 1.0f : 0.0f;

    const float w00 = wx0 * wy0 * vx0 * vy0;
    const float w10 = wx1 * wy0 * vx1 * vy0;
    const float w01 = wx0 * wy1 * vx0 * vy1;
    const float w11 = wx1 * wy1 * vx1 * vy1;

    const int xc0 = min(max(x0, 0), W - 1);
    const int xc1 = min(max(x1, 0), W - 1);
    const int yc0 = min(max(y0, 0), H - 1);
    const int yc1 = min(max(y1, 0), H - 1);

    const int o00 = yc0 * W + xc0;
    const int o10 = yc0 * W + xc1;
    const int o01 = yc1 * W + xc0;
    const int o11 = yc1 * W + xc1;

#pragma unroll
    for (int c = 0; c < C; ++c) {
        const float* __restrict__ xc = x + c * HW;
        const float v = xc[o00] * w00 + xc[o10] * w10
                      + xc[o01] * w01 + xc[o11] * w11;
        out[c * HW + tid] = v;
    }
}

extern "C" void kernel_launch(void* const* d_in, const int* in_sizes, int n_in,
                              void* d_out, int out_size, void* d_ws, size_t ws_size,
                              hipStream_t stream) {
    const float* flow = (const float*)d_in[0];  // [1,2,1024,1024]
    const float* x    = (const float*)d_in[1];  // [1,32,1024,1024]
    float* out        = (float*)d_out;          // [1,32,1024,1024]

    const size_t need = (size_t)HW * C * sizeof(float);  // 128 MB
    if (ws_size >= need) {
        float* xp = (float*)d_ws;
        transpose_kernel<<<HW / TP_PX, 256, 0, stream>>>(x, xp);
        gather_v3<<<HW / GP_PX, 256, 0, stream>>>(flow, xp, out);
    } else {
        stn_warp_fallback<<<HW / 256, 256, 0, stream>>>(flow, x, out);
    }
}